// Round 12
// baseline (414.124 us; speedup 1.0000x reference)
//
#include <hip/hip_runtime.h>

#if __has_builtin(__builtin_amdgcn_exp2f)
#define EXP2F(x) __builtin_amdgcn_exp2f(x)
#else
#define EXP2F(x) exp2f(x)
#endif
#if __has_builtin(__builtin_amdgcn_rcpf)
#define RCPF(x) __builtin_amdgcn_rcpf(x)
#else
#define RCPF(x) (1.0f / (x))
#endif

namespace {

constexpr int B_ = 2048, T_ = 512, D_ = 8, H_ = 20, L_ = 10;
constexpr int NG    = 16;        // batch group per block (MFMA N)
constexpr int PADK  = 24;        // shorts per [batch] h row (48B; 2-way banks)
constexpr int NW    = 11;        // 10 layer waves + 1 head wave
constexpr int NTHR  = NW * 64;   // 704
constexpr int DEPTH = 8;         // h ring depth
constexpr int SLOT_STRIDE  = L_ * NG * PADK;  // 3840 shorts
constexpr int LAYER_STRIDE = NG * PADK;       // 384 shorts

typedef float f32x4 __attribute__((ext_vector_type(4)));
typedef short s16x4 __attribute__((ext_vector_type(4)));  // 4 bf16, 2 VGPRs

#define LD4(p) (*reinterpret_cast<const f32x4*>(p))

__device__ __forceinline__ unsigned short f2bf(float f) {
    unsigned u = __builtin_bit_cast(unsigned, f);
    return (unsigned short)((u + 0x7FFFu + ((u >> 16) & 1u)) >> 16);
}
__device__ __forceinline__ float bf2f(unsigned short b) {
    return __builtin_bit_cast(float, (unsigned)b << 16);
}
__device__ __forceinline__ unsigned cvt_pk_bf16(float s0, float s1) {
    unsigned r;
    asm("v_cvt_pk_bf16_f32 %0, %1, %2" : "=v"(r) : "v"(s0), "v"(s1));
    return r;
}
__device__ __forceinline__ float tanh_fast(float x) {
    float e = EXP2F(x * 2.8853900817779268f);
    return fmaf(-2.0f, RCPF(1.0f + e), 1.0f);
}

// K=16 MFMA: B-frag layout == D layout -> h_next (pw,qw) IS next step's
// B operand. Inline asm (mnemonic per cdna4_isa.md §10).
__device__ __forceinline__ f32x4 mfma16(s16x4 a, s16x4 b, f32x4 c) {
    asm("v_mfma_f32_16x16x16_bf16 %0, %1, %2, %0"
        : "+v"(c) : "v"(a), "v"(b));
    return c;
}

// hi/lo split weight fragment (exact fp32 weights across 2 MFMAs)
struct AF { s16x4 hi, lo; };
__device__ __forceinline__ AF mkfrag(float v0, float v1, float v2, float v3) {
    AF f; float v[4] = {v0, v1, v2, v3};
    #pragma unroll
    for (int e = 0; e < 4; ++e) {
        unsigned short h = f2bf(v[e]);
        f.hi[e] = (short)h; f.lo[e] = (short)f2bf(v[e] - bf2f(h));
    }
    return f;
}

// acquire-poll with s_sleep backoff (R8-R11 lesson: bare spin loops hammer
// the LDS pipe ~every 40cy per waiting wave -> congestion on the shared pipe)
__device__ __forceinline__ int wait_ge_ret(int* p, int v) {
    int cur = __hip_atomic_load(p, __ATOMIC_ACQUIRE, __HIP_MEMORY_SCOPE_WORKGROUP);
    while (cur < v) {
        __builtin_amdgcn_s_sleep(1);
        cur = __hip_atomic_load(p, __ATOMIC_ACQUIRE, __HIP_MEMORY_SCOPE_WORKGROUP);
    }
    __builtin_amdgcn_sched_barrier(0);
    return cur;
}
__device__ __forceinline__ void publish(int* p, int v) {
    asm volatile("s_waitcnt lgkmcnt(0)" ::: "memory");
    __hip_atomic_store(p, v, __ATOMIC_RELAXED, __HIP_MEMORY_SCOPE_WORKGROUP);
}

// x B-frag: Ktile cols [0..7]=x_hi, [8..15]=x_lo; lane(col,g) holds k=g*4+e
__device__ __forceinline__ s16x4 pack_x4(f32x4 a, f32x4 b, int g) {
    s16x4 r;
    #pragma unroll
    for (int e = 0; e < 4; ++e) {
        int k = ((g & 1) << 2) + e;          // x element 0..7
        float f = (k < 4) ? a[k] : b[k - 4];
        unsigned short h = f2bf(f);
        r[e] = (short)((g < 2) ? h : f2bf(f - bf2f(h)));
    }
    return r;
}

// Self-timed wavefront (R10 protocol) + K=16 D->B identity:
// wave w = layer w, wave 10 = head; prog[] handoff, DEPTH=8 ring.
// Own-h recurrence is 100% register-resident (no LDS, no shfl); cross-wave
// handoff = 2 b64 stores / 2 b64 reads per step in matching per-lane layout.
__global__ __launch_bounds__(NTHR) void rnn_async(
    const float* __restrict__ x,      const float* __restrict__ w_ih0,
    const float* __restrict__ w_ih,   const float* __restrict__ w_hh,
    const float* __restrict__ b_ih,   const float* __restrict__ b_hh,
    const float* __restrict__ fc_w,   const float* __restrict__ fc_b,
    const float* __restrict__ l2_w,   const float* __restrict__ l2_b,
    float* __restrict__ out)          // [B,T] flat
{
    __shared__ __align__(16) unsigned short h_lds[DEPTH][L_][NG][PADK]; // 61.4KB
    __shared__ int prog[16];

    const int tid = threadIdx.x;
    const int w   = tid >> 6;       // 0..9 layer wave, 10 head
    const int l   = tid & 63;
    const int col = l & 15;         // batch (B,D) / weight row m (A)
    const int g   = l >> 4;         // k-group (B) / row-group (D)
    const int bg  = blockIdx.x * NG;

    {   // zero ring (h0=0; pad shorts 20..23 stay 0) + prog
        uint4* p4 = reinterpret_cast<uint4*>(&h_lds[0][0][0][0]);
        for (int i = tid; i < DEPTH * SLOT_STRIDE / 8; i += NTHR)
            p4[i] = make_uint4(0, 0, 0, 0);
        if (tid < 16) prog[tid] = 0;
    }

    // ---- weight fragments: A(m=col|16+col, k=g*4+e | 16+e) ----
    AF iA0, iA1, iB0, iB1;   // W_ih: Ktile0 m0/m1, Ktile1 m0/m1
    AF hA0, hA1, hB0, hB1;   // W_hh
    f32x4 bias0 = {0.f,0.f,0.f,0.f}, bias1 = bias0, l2v0 = bias0, l2v1 = bias0;
    float l2bv = 0.f;
    const bool m1ok = col < 4;      // Mtile1 rows 16+col valid
    const int k0 = g * 4;

    if (w < L_) {
        if (w == 0) {               // x-packed: A[m][k] = w_ih0[m][(g&1)*4+e]
            const int kx = ((g & 1) << 2);
            const float* r0 = w_ih0 + col * D_ + kx;
            iA0 = mkfrag(r0[0], r0[1], r0[2], r0[3]);
            const float* r1 = w_ih0 + (16 + col) * D_ + kx;
            iA1 = m1ok ? mkfrag(r1[0], r1[1], r1[2], r1[3]) : mkfrag(0,0,0,0);
            iB0 = mkfrag(0,0,0,0); iB1 = mkfrag(0,0,0,0);
        } else {
            const float* Wm0 = w_ih + ((w - 1) * H_ + col) * H_;
            const float* Wm1 = w_ih + ((w - 1) * H_ + 16 + col) * H_;
            iA0 = mkfrag(Wm0[k0], Wm0[k0+1], Wm0[k0+2], Wm0[k0+3]);
            iA1 = m1ok ? mkfrag(Wm1[k0], Wm1[k0+1], Wm1[k0+2], Wm1[k0+3])
                       : mkfrag(0,0,0,0);
            iB0 = (g == 0) ? mkfrag(Wm0[16], Wm0[17], Wm0[18], Wm0[19])
                           : mkfrag(0,0,0,0);
            iB1 = (g == 0 && m1ok)
                           ? mkfrag(Wm1[16], Wm1[17], Wm1[18], Wm1[19])
                           : mkfrag(0,0,0,0);
        }
        const float* Um0 = w_hh + (w * H_ + col) * H_;
        const float* Um1 = w_hh + (w * H_ + 16 + col) * H_;
        hA0 = mkfrag(Um0[k0], Um0[k0+1], Um0[k0+2], Um0[k0+3]);
        hA1 = m1ok ? mkfrag(Um1[k0], Um1[k0+1], Um1[k0+2], Um1[k0+3])
                   : mkfrag(0,0,0,0);
        hB0 = (g == 0) ? mkfrag(Um0[16], Um0[17], Um0[18], Um0[19])
                       : mkfrag(0,0,0,0);
        hB1 = (g == 0 && m1ok) ? mkfrag(Um1[16], Um1[17], Um1[18], Um1[19])
                               : mkfrag(0,0,0,0);
        #pragma unroll
        for (int r = 0; r < 4; ++r) {
            const int row = g * 4 + r;
            bias0[r] = b_ih[w * H_ + row] + b_hh[w * H_ + row];
            bias1[r] = (g == 0) ? (b_ih[w * H_ + 16 + r] +
                                   b_hh[w * H_ + 16 + r]) : 0.f;
        }
    } else {
        const float* Fm0 = fc_w + col * H_;
        const float* Fm1 = fc_w + (16 + col) * H_;
        iA0 = mkfrag(Fm0[k0], Fm0[k0+1], Fm0[k0+2], Fm0[k0+3]);
        iA1 = m1ok ? mkfrag(Fm1[k0], Fm1[k0+1], Fm1[k0+2], Fm1[k0+3])
                   : mkfrag(0,0,0,0);
        iB0 = (g == 0) ? mkfrag(Fm0[16], Fm0[17], Fm0[18], Fm0[19])
                       : mkfrag(0,0,0,0);
        iB1 = (g == 0 && m1ok) ? mkfrag(Fm1[16], Fm1[17], Fm1[18], Fm1[19])
                               : mkfrag(0,0,0,0);
        hA0 = hA1 = hB0 = hB1 = mkfrag(0,0,0,0);
        #pragma unroll
        for (int r = 0; r < 4; ++r) {
            bias0[r] = fc_b[g * 4 + r];
            bias1[r] = (g == 0) ? fc_b[16 + r] : 0.f;
            l2v0[r]  = l2_w[g * 4 + r];
            l2v1[r]  = (g == 0) ? l2_w[16 + r] : 0.f;
        }
        l2bv = l2_b[0];
    }

    // wave-0 x prefetch, 2 deep, packed at load (2 VGPR/slot)
    s16x4 xf_cur = {0,0,0,0}, xf_nxt = xf_cur;
    if (w == 0) {
        const float* xp = x + (size_t)(bg + col) * T_ * D_;
        xf_cur = pack_x4(LD4(xp), LD4(xp + 4), g);
        xf_nxt = pack_x4(LD4(xp + D_), LD4(xp + D_ + 4), g);
    }

    __syncthreads();  // ONLY barrier

    unsigned short* const hb = &h_lds[0][0][0][0];
    const f32x4 z4 = {0.f, 0.f, 0.f, 0.f};
    const s16x4 zb = {0, 0, 0, 0};

    if (w < L_) {
        const int rdB0 = (w ? (w - 1) * LAYER_STRIDE : 0) + col * PADK;
        const int wr0  = w * LAYER_STRIDE + col * PADK + g * 4;
        const int wr1  = w * LAYER_STRIDE + col * PADK + 16;
        uint2 pw = make_uint2(0u, 0u), qw = pw;   // h[t-1]; ALSO next B1 frags
        int p_up = 0, p_dn = 0;
        for (int t = 0; t < T_; ++t) {
            const int sc = (t & (DEPTH - 1)) * SLOT_STRIDE;
            const s16x4 b1t0 = __builtin_bit_cast(s16x4, pw);  // D->B identity
            const s16x4 b1t1 = __builtin_bit_cast(s16x4, qw);  // 0 on g>0 lanes
            s16x4 b0t0, b0t1;
            if (w == 0) {
                b0t0 = xf_cur; b0t1 = zb;
                xf_cur = xf_nxt;
                if (t + 2 < T_) {
                    const float* xp = x + ((size_t)(bg + col) * T_ + t + 2) * D_;
                    xf_nxt = pack_x4(LD4(xp), LD4(xp + 4), g);
                }
            } else {
                if (p_up < t + 1) p_up = wait_ge_ret(&prog[w - 1], t + 1);
                const unsigned short* rp = hb + sc + rdB0;
                b0t0 = __builtin_bit_cast(s16x4,
                        *reinterpret_cast<const uint2*>(rp + g * 4));
                b0t1 = (g == 0) ? __builtin_bit_cast(s16x4,
                        *reinterpret_cast<const uint2*>(rp + 16)) : zb;
            }
            // 4 parallel 3-4 deep chains
            f32x4 acc   = mfma16(iA0.hi, b0t0, bias0);
            f32x4 acc1  = mfma16(iA1.hi, b0t0, bias1);
            f32x4 accb  = mfma16(iA0.lo, b0t0, z4);
            f32x4 acc1b = mfma16(iA1.lo, b0t0, z4);
            if (w != 0) {   // wave-uniform branch
                acc   = mfma16(iB0.hi, b0t1, acc);
                acc1  = mfma16(iB1.hi, b0t1, acc1);
                accb  = mfma16(iB0.lo, b0t1, accb);
                acc1b = mfma16(iB1.lo, b0t1, acc1b);
            }
            acc   = mfma16(hA0.hi, b1t0, acc);
            acc1  = mfma16(hA1.hi, b1t0, acc1);
            accb  = mfma16(hA0.lo, b1t0, accb);
            acc1b = mfma16(hA1.lo, b1t0, acc1b);
            acc   = mfma16(hB0.hi, b1t1, acc);
            acc1  = mfma16(hB1.hi, b1t1, acc1);
            accb  = mfma16(hB0.lo, b1t1, accb);
            acc1b = mfma16(hB1.lo, b1t1, acc1b);
            acc += accb; acc1 += acc1b;
            pw.x = cvt_pk_bf16(tanh_fast(acc[0]),  tanh_fast(acc[1]));
            pw.y = cvt_pk_bf16(tanh_fast(acc[2]),  tanh_fast(acc[3]));
            qw.x = cvt_pk_bf16(tanh_fast(acc1[0]), tanh_fast(acc1[1]));
            qw.y = cvt_pk_bf16(tanh_fast(acc1[2]), tanh_fast(acc1[3]));
            // WAR: slot reused from t-DEPTH; consumer must be past it
            if (t >= DEPTH && p_dn < t - DEPTH + 1)
                p_dn = wait_ge_ret(&prog[w + 1], t - DEPTH + 1);
            *reinterpret_cast<uint2*>(hb + sc + wr0) = pw;
            if (g == 0) *reinterpret_cast<uint2*>(hb + sc + wr1) = qw;
            if (l == 0) publish(&prog[w], t + 1);
        }
    } else {
        const int rdH = (L_ - 1) * LAYER_STRIDE + col * PADK;
        int p_up = 0;
        for (int t = 0; t < T_; ++t) {
            if (p_up < t + 1) p_up = wait_ge_ret(&prog[L_ - 1], t + 1);
            const unsigned short* rp =
                hb + (t & (DEPTH - 1)) * SLOT_STRIDE + rdH;
            s16x4 bt0 = __builtin_bit_cast(s16x4,
                    *reinterpret_cast<const uint2*>(rp + g * 4));
            s16x4 bt1 = (g == 0) ? __builtin_bit_cast(s16x4,
                    *reinterpret_cast<const uint2*>(rp + 16)) : zb;
            f32x4 z0  = mfma16(iA0.hi, bt0, bias0);
            f32x4 z1  = mfma16(iA1.hi, bt0, bias1);
            f32x4 z0b = mfma16(iA0.lo, bt0, z4);
            f32x4 z1b = mfma16(iA1.lo, bt0, z4);
            z0  = mfma16(iB0.hi, bt1, z0);
            z1  = mfma16(iB1.hi, bt1, z1);
            z0b = mfma16(iB0.lo, bt1, z0b);
            z1b = mfma16(iB1.lo, bt1, z1b);
            z0 += z0b; z1 += z1b;
            float part = 0.f;
            #pragma unroll
            for (int r = 0; r < 4; ++r) {
                part = fmaf(l2v0[r], fmaxf(z0[r], 0.f), part);
                part = fmaf(l2v1[r], fmaxf(z1[r], 0.f), part);
            }
            part += __shfl_xor(part, 16);
            part += __shfl_xor(part, 32);
            if (l < NG) out[(size_t)(bg + l) * T_ + t] = part + l2bv;
            if (l == 0) publish(&prog[L_], t + 1);  // "h[9][t] read done"
        }
    }
}

}  // namespace

extern "C" void kernel_launch(void* const* d_in, const int* in_sizes, int n_in,
                              void* d_out, int out_size, void* d_ws, size_t ws_size,
                              hipStream_t stream) {
    const float* x     = (const float*)d_in[0];
    const float* w_ih0 = (const float*)d_in[1];
    const float* w_ih  = (const float*)d_in[2];
    const float* w_hh  = (const float*)d_in[3];
    const float* b_ih  = (const float*)d_in[4];
    const float* b_hh  = (const float*)d_in[5];
    const float* fc_w  = (const float*)d_in[6];
    const float* fc_b  = (const float*)d_in[7];
    const float* l2_w  = (const float*)d_in[8];
    const float* l2_b  = (const float*)d_in[9];
    float* out = (float*)d_out;

    const int grid = B_ / NG;  // 128
    hipLaunchKernelGGL(rnn_async, dim3(grid), dim3(NTHR), 0, stream,
                       x, w_ih0, w_ih, w_hh, b_ih, b_hh, fc_w, fc_b,
                       l2_w, l2_b, out);
}